// Round 1
// baseline (253.102 us; speedup 1.0000x reference)
//
#include <hip/hip_runtime.h>

// Problem constants (from reference)
#define BATCH 128
#define SEQ   2000
#define EMB   50          // 200 B per row (only 8B-aligned: idx*200 % 16 = 8 for odd idx)
#define OUTD  2

// Tiling: a 32-lane group cooperates on one embedding row; lanes 0..24 each
// load one contiguous float2 of the row, so the coalescer merges the row
// into ~2-3 cache-line transactions (vs 13-25 scattered ones before).
#define CHUNKS 25                      // seq chunks per batch row
#define RPB    (SEQ / CHUNKS)          // 80 rows per block
#define TPB    256
#define WAVES  (TPB / 64)
#define GRP    32                      // lanes per group
#define NGRP   (TPB / GRP)             // 8 groups per block
#define RPG    (RPB / NGRP)            // 10 rows per group (all loads unrolled/in-flight)
#define LPR    (EMB / 2)               // 25 active float2 lanes per row

// Kernel 1: block = (chunk c, batch b). Stage the chunk's 80 indices into
// LDS (coalesced), then each 32-lane group streams 10 rows: lane j<25 loads
// row[2j:2j+2] (contiguous across lanes -> line-merged), folds the 50->2
// linear layer on the fly with its private W fragment, masks -1 padding.
// Full-wave shuffle reduction + cross-wave LDS reduce -> 2-float partial.
__global__ __launch_bounds__(TPB) void embbag_partial_kernel(
    const int* __restrict__ t,          // [BATCH, SEQ]
    const float* __restrict__ emb,      // [VOCAB, EMB]
    const float* __restrict__ W,        // [OUTD, EMB]
    float* __restrict__ partial)        // [BATCH, CHUNKS, OUTD]
{
    __shared__ int sIdx[RPB];
    __shared__ float2 red[WAVES];

    const int tid = threadIdx.x;
    const int c = blockIdx.x;
    const int b = blockIdx.y;

    if (tid < RPB) sIdx[tid] = t[b * SEQ + c * RPB + tid];
    __syncthreads();

    const int g = tid >> 5;            // group 0..7
    const int j = tid & 31;            // lane within group

    float a0 = 0.0f, a1 = 0.0f;
    if (j < LPR) {                     // single divergence point; lanes 25..31 idle
        // per-lane W fragment: (W0[2j],W0[2j+1]) and (W1[2j],W1[2j+1]), 8B-aligned
        const float2 w0 = *(const float2*)(W + 2 * j);
        const float2 w1 = *(const float2*)(W + EMB + 2 * j);
        const int* gi = sIdx + g * RPG;
#pragma unroll
        for (int r = 0; r < RPG; ++r) {
            const int idx = gi[r];     // LDS broadcast (same addr across group)
            const size_t off = (size_t)((idx < 0) ? 0 : idx) * EMB + 2 * j;
            float2 e = *(const float2*)(emb + off);   // 8B aligned always
            if (idx < 0) { e.x = 0.0f; e.y = 0.0f; }  // -1 = padding -> 0
            a0 = fmaf(e.x, w0.x, fmaf(e.y, w0.y, a0));
            a1 = fmaf(e.x, w1.x, fmaf(e.y, w1.y, a1));
        }
    }

    // wave (64-lane) shuffle reduction — inactive lanes contribute 0
#pragma unroll
    for (int off = 32; off > 0; off >>= 1) {
        a0 += __shfl_down(a0, off, 64);
        a1 += __shfl_down(a1, off, 64);
    }
    const int wave = tid >> 6;
    const int lane = tid & 63;
    if (lane == 0) red[wave] = make_float2(a0, a1);
    __syncthreads();

    if (tid == 0) {
        float s0 = 0.0f, s1 = 0.0f;
#pragma unroll
        for (int w = 0; w < WAVES; ++w) { s0 += red[w].x; s1 += red[w].y; }
        float* p = partial + ((size_t)b * CHUNKS + c) * OUTD;
        p[0] = s0;
        p[1] = s1;
    }
}

// Kernel 2: one (b,o) pair per thread: sum CHUNKS partials, /BATCH, +bias, relu.
__global__ __launch_bounds__(TPB) void finalize_kernel(
    const float* __restrict__ partial,  // [BATCH, CHUNKS, OUTD]
    const float* __restrict__ bias,     // [OUTD]
    float* __restrict__ out)            // [BATCH, OUT]
{
    const int i = threadIdx.x;
    if (i < BATCH * OUTD) {
        const int b = i >> 1;
        const int o = i & 1;
        float s = 0.0f;
#pragma unroll
        for (int cc = 0; cc < CHUNKS; ++cc)
            s += partial[((size_t)b * CHUNKS + cc) * OUTD + o];
        s = s * (1.0f / (float)BATCH) + bias[o];
        out[i] = fmaxf(s, 0.0f);
    }
}

extern "C" void kernel_launch(void* const* d_in, const int* in_sizes, int n_in,
                              void* d_out, int out_size, void* d_ws, size_t ws_size,
                              hipStream_t stream) {
    const int*   t    = (const int*)d_in[0];
    const float* emb  = (const float*)d_in[1];
    const float* W    = (const float*)d_in[2];
    const float* bias = (const float*)d_in[3];
    float* out        = (float*)d_out;
    float* partial    = (float*)d_ws;   // BATCH*CHUNKS*OUTD floats = 25.6 KB

    dim3 grid(CHUNKS, BATCH);
    embbag_partial_kernel<<<grid, TPB, 0, stream>>>(t, emb, W, partial);
    finalize_kernel<<<1, TPB, 0, stream>>>(partial, bias, out);
}

// Round 2
// 252.849 us; speedup vs baseline: 1.0010x; 1.0010x over previous
//
#include <hip/hip_runtime.h>

// Problem constants (from reference)
#define BATCH 128
#define SEQ   2000
#define EMB   50          // 200 B per row; idx*200 is only 8B-aligned -> float2 loads
#define OUTD  2

// Single fused kernel: one block per batch row, NO workspace (d_ws untouched).
// Theory: the ~240us floor is two 800MB poison-fills of the workspace inside
// the timed graph; the gather itself is ~10-20us (emb table is L3-resident).
#define TPB    512
#define WAVES  (TPB / 64)              // 8 waves/CU -> 2 per SIMD, latency hiding
#define GRP    32                      // lanes per group; lanes 0..24 active
#define NGRP   (TPB / GRP)             // 16 groups
#define RPG    (SEQ / NGRP)            // 125 rows per group
#define LPR    (EMB / 2)               // 25 float2 slots per row

__global__ __launch_bounds__(TPB) void embbag_fused_kernel(
    const int* __restrict__ t,          // [BATCH, SEQ]
    const float* __restrict__ emb,      // [VOCAB, EMB]
    const float* __restrict__ W,        // [OUTD, EMB]
    const float* __restrict__ bias,     // [OUTD]
    float* __restrict__ out)            // [BATCH, OUTD]
{
    __shared__ int sIdx[SEQ];           // 8 KB, coalesced stage of this row's indices
    __shared__ float2 red[WAVES];

    const int tid = threadIdx.x;
    const int b = blockIdx.x;

    // coalesced index staging
    for (int i = tid; i < SEQ; i += TPB) sIdx[i] = t[b * SEQ + i];
    __syncthreads();

    const int g = tid >> 5;            // group 0..15
    const int j = tid & 31;            // lane within group

    float a0 = 0.0f, a1 = 0.0f;
    if (j < LPR) {                     // lanes 25..31 idle (78% lane util, fine)
        // per-lane W fragment: (W0[2j],W0[2j+1]) and (W1[2j],W1[2j+1])
        const float2 w0 = *(const float2*)(W + 2 * j);
        const float2 w1 = *(const float2*)(W + EMB + 2 * j);
        const int* gi = sIdx + g * RPG;
#pragma unroll 5
        for (int r = 0; r < RPG; ++r) {
            const int idx = gi[r];     // LDS broadcast across the group
            const size_t off = (size_t)((idx < 0) ? 0 : idx) * EMB + 2 * j;
            float2 e = *(const float2*)(emb + off);   // 8B aligned, line-merged
            if (idx < 0) { e.x = 0.0f; e.y = 0.0f; }  // -1 padding -> 0
            a0 = fmaf(e.x, w0.x, fmaf(e.y, w0.y, a0));
            a1 = fmaf(e.x, w1.x, fmaf(e.y, w1.y, a1));
        }
    }

    // wave (64-lane) shuffle reduction — sums both 32-lane groups in the wave
#pragma unroll
    for (int off = 32; off > 0; off >>= 1) {
        a0 += __shfl_down(a0, off, 64);
        a1 += __shfl_down(a1, off, 64);
    }
    const int wave = tid >> 6;
    const int lane = tid & 63;
    if (lane == 0) red[wave] = make_float2(a0, a1);
    __syncthreads();

    // final: scale by 1/BATCH (reference divides by t.shape[0]), +bias, relu
    if (tid == 0) {
        float s0 = 0.0f, s1 = 0.0f;
#pragma unroll
        for (int w = 0; w < WAVES; ++w) { s0 += red[w].x; s1 += red[w].y; }
        const float inv = 1.0f / (float)BATCH;
        out[b * OUTD + 0] = fmaxf(fmaf(s0, inv, bias[0]), 0.0f);
        out[b * OUTD + 1] = fmaxf(fmaf(s1, inv, bias[1]), 0.0f);
    }
}

extern "C" void kernel_launch(void* const* d_in, const int* in_sizes, int n_in,
                              void* d_out, int out_size, void* d_ws, size_t ws_size,
                              hipStream_t stream) {
    const int*   t    = (const int*)d_in[0];
    const float* emb  = (const float*)d_in[1];
    const float* W    = (const float*)d_in[2];
    const float* bias = (const float*)d_in[3];
    float* out        = (float*)d_out;
    (void)d_ws; (void)ws_size;          // workspace deliberately unused

    embbag_fused_kernel<<<BATCH, TPB, 0, stream>>>(t, emb, W, bias, out);
}